// Round 5
// baseline (123.572 us; speedup 1.0000x reference)
//
#include <hip/hip_runtime.h>

// CatmullRomActivation — MI355X (gfx950), round 5: fine-grained TLP.
//
// Reference quirk: coef is sample-major flat, Q is neuron-major flat, multiplied
// on the same linear index q. So for out.flat[q]:
//   u-part   : x.flat[q]                     (linear, coalesced)
//   p0/points: x[iq][jq], jq=q/M, iq=q%M     (transposed traversal, cp row jq)
//
// History: R1 one-shot 64x64 blocks 41.4us; R3 +prefetch/NT ~38us; R4
// 4-tile pipeline REGRESSED to 46.9us (occupancy 29%) -> TLP beats in-block
// pipelining here. R5: 128-thread blocks / 32x64 tiles -> 8192 blocks,
// 15 resident/CU (30 waves), finer interleave of load/compute phases across
// independent blocks. Barrier is lgkm-only (s_barrier without vmcnt drain,
// m139 pattern) so pre-issued linear loads stay in flight across it.

constexpr int M_DIM  = 8192;   // samples
constexpr int N_DIM  = 2048;   // neurons
constexpr int KPTS   = 10;     // control points per neuron
constexpr int TILE_I = 32;     // iq extent per block
constexpr int TILE_J = 64;     // jq (neuron) extent per block
constexpr int PITCH  = TILE_J + 1;  // 65: transposed reads 2-way max (free)
constexpr int NTHR   = 128;

typedef float floatx4 __attribute__((ext_vector_type(4)));

__device__ __forceinline__ void lgkm_barrier() {
    // __syncthreads() drains vmcnt(0) too; we only need LDS visibility.
    asm volatile("s_waitcnt lgkmcnt(0)" ::: "memory");
    __builtin_amdgcn_s_barrier();
    asm volatile("" ::: "memory");
}

__global__ __launch_bounds__(NTHR)
void catmull_rom_kernel(const float* __restrict__ x,
                        const float* __restrict__ cp,
                        float* __restrict__ out)
{
    __shared__ float xt[TILE_I * PITCH];   // xt[r*PITCH+c] = x[iq0+r][jq0+c]
    __shared__ float cps[TILE_J * KPTS];   // cps[c*KPTS+k] = cp[jq0+c][k]

    const int t   = threadIdx.x;
    const int iq0 = blockIdx.x * TILE_I;
    const int jq0 = blockIdx.y * TILE_J;

    // ---- issue tile loads (barrier-critical) ----
    float4 tv[4];
    #pragma unroll
    for (int k = 0; k < 4; ++k) {
        int f = t + k * NTHR;              // 0..511 float4 units
        int r = f >> 4, c4 = (f & 15) << 2;
        tv[k] = *reinterpret_cast<const float4*>(
            x + (size_t)(iq0 + r) * N_DIM + (jq0 + c4));
    }
    // ---- cp loads: 640 floats over 128 threads = 5 each, no bounds check ----
    const float* cpb = cp + (size_t)jq0 * KPTS;
    float cv[5];
    #pragma unroll
    for (int i = 0; i < 5; ++i) cv[i] = cpb[t + i * NTHR];

    // ---- linear loads: LDS-independent, consumed only after the barrier;
    //      lgkm-only barrier keeps them in flight across it ----
    float4 xl[4];
    size_t q[4];
    #pragma unroll
    for (int k = 0; k < 4; ++k) {
        int f  = t + k * NTHR;
        int tj = f >> 3;                   // neuron-in-tile 0..63
        int g  = (f & 7) << 2;             // iq_local base 0..28
        q[k]  = (size_t)(jq0 + tj) * M_DIM + (size_t)(iq0 + g);
        xl[k] = *reinterpret_cast<const float4*>(x + q[k]);
    }

    // ---- stage tile + cp to LDS ----
    #pragma unroll
    for (int k = 0; k < 4; ++k) {
        int f = t + k * NTHR;
        int r = f >> 4, c4 = (f & 15) << 2;
        float* dst = &xt[r * PITCH + c4];
        dst[0] = tv[k].x; dst[1] = tv[k].y; dst[2] = tv[k].z; dst[3] = tv[k].w;
    }
    #pragma unroll
    for (int i = 0; i < 5; ++i) cps[t + i * NTHR] = cv[i];

    lgkm_barrier();

    // ---- compute + store: 2048 outputs/block, 16/thread as 4x float4 ----
    #pragma unroll
    for (int k = 0; k < 4; ++k) {
        int f  = t + k * NTHR;
        int tj = f >> 3;
        int g  = (f & 7) << 2;
        const float* cpn = &cps[tj * KPTS];
        float xle[4] = {xl[k].x, xl[k].y, xl[k].z, xl[k].w};
        float res[4];
        #pragma unroll
        for (int e = 0; e < 4; ++e) {
            float xv_t = xt[(g + e) * PITCH + tj];      // transposed value
            float p0f  = floorf((xv_t + 2.0f) * 1.5f + 1.0f);
            int   p0   = (int)p0f;
            p0 = (xv_t <= -2.0f) ? 1 : p0;
            p0 = (xv_t >=  2.0f) ? 7 : p0;

            float Pm1 = cpn[p0 - 1];
            float P0  = cpn[p0];
            float P1  = cpn[p0 + 1];
            float P2  = cpn[p0 + 2];

            float xv = xle[e];
            float tt = 2.0f * xv;            // x / 0.5
            float u  = tt - floorf(tt);
            float u2 = u * u;
            float u3 = u2 * u;
            float c0 = -0.5f*u3 +       u2 - 0.5f*u;   // pairs P2
            float c1 =  1.5f*u3 - 2.5f*u2 + 1.0f;      // pairs P1
            float c2 = -1.5f*u3 + 2.0f*u2 + 0.5f*u;    // pairs P0
            float c3 =  0.5f*u3 - 0.5f*u2;             // pairs Pm1
            res[e] = c3*Pm1 + c2*P0 + c1*P1 + c0*P2;
        }
        floatx4 ov = {res[0], res[1], res[2], res[3]};
        __builtin_nontemporal_store(ov, reinterpret_cast<floatx4*>(out + q[k]));
    }
}

extern "C" void kernel_launch(void* const* d_in, const int* in_sizes, int n_in,
                              void* d_out, int out_size, void* d_ws, size_t ws_size,
                              hipStream_t stream) {
    const float* x  = (const float*)d_in[0];   // (M, N) f32
    const float* cp = (const float*)d_in[1];   // (N, K) f32
    float* out = (float*)d_out;                // (M, N) f32

    dim3 grid(M_DIM / TILE_I, N_DIM / TILE_J);   // (256, 32) = 8192 blocks
    dim3 block(NTHR);
    catmull_rom_kernel<<<grid, block, 0, stream>>>(x, cp, out);
}

// Round 6
// 117.003 us; speedup vs baseline: 1.0561x; 1.0561x over previous
//
#include <hip/hip_runtime.h>

// CatmullRomActivation — MI355X (gfx950), round 6: kill LDS instruction volume.
//
// Reference quirk: coef is sample-major flat, Q is neuron-major flat, multiplied
// on the same linear index q. So for out.flat[q]:
//   u-part   : x.flat[q]                     (linear, coalesced)
//   p0/points: x[iq][jq], jq=q/M, iq=q%M     (transposed traversal, cp row jq)
//
// History: R1 41.4us; R3 (+prefetch,NT) ~38us; R4 4-tile pipeline 46.9us
// (occupancy collapse); R5 128-thr+lgkm ~44us. Limiter: ~101 LDS insts/thread
// (~15.6us of LDS-pipe serialization/CU vs 21us HBM floor).
// R6: (a) per-(neuron,seg) cubic coeff table as float4 -> 4-pt gather becomes
// ONE ds_read_b128 (64->16 insts); (b) segment index computed at staging and
// byte-packed 4-wide -> staging writes 16->4, transposed reads 16->4 (one
// packed word serves all 4 k's since tj = 4*(t>>4)+k). 26 LDS insts/thread.

constexpr int M_DIM  = 8192;   // samples
constexpr int N_DIM  = 2048;   // neurons
constexpr int KPTS   = 10;     // control points per neuron
constexpr int TILE   = 64;     // 64 x 64 tile
constexpr int PITCHW = 17;     // u32 words per seg-pack row (16 + 1 pad)
constexpr int NSEG   = 7;      // segments per neuron (p0 in [1,7])

typedef float floatx4 __attribute__((ext_vector_type(4)));

__device__ __forceinline__ int seg_of(float v) {
    float p0f = floorf((v + 2.0f) * 1.5f + 1.0f);   // matches ref arithmetic
    int   p0  = (int)p0f;
    p0 = (v <= -2.0f) ? 1 : p0;
    p0 = (v >=  2.0f) ? 7 : p0;
    return p0 - 1;                                   // seg in [0,6]
}

__global__ __launch_bounds__(256)
void catmull_rom_kernel(const float* __restrict__ x,
                        const float* __restrict__ cp,
                        float* __restrict__ out)
{
    __shared__ unsigned int segp[TILE * PITCHW];     // packed segs, 4.35 KB
    __shared__ floatx4 coefs[TILE * NSEG];           // cubic coeffs, 7.17 KB

    const int t   = threadIdx.x;
    const int iq0 = blockIdx.x * TILE;
    const int jq0 = blockIdx.y * TILE;
    const int a   = t >> 4;            // 0..15
    const int g   = (t & 15) << 2;     // iq_local base 0..60

    // ---- issue tile loads (barrier-critical) ----
    float4 tv[4];
    #pragma unroll
    for (int k = 0; k < 4; ++k) {
        int f = t + k * 256;
        int r = f >> 4, c4 = (f & 15) << 2;
        tv[k] = *reinterpret_cast<const float4*>(
            x + (size_t)(iq0 + r) * N_DIM + (jq0 + c4));
    }
    // ---- linear loads: LDS-independent, consumed after barrier ----
    float4 xl[4];
    size_t q[4];
    #pragma unroll
    for (int k = 0; k < 4; ++k) {
        int tj = 4 * a + k;
        q[k]  = (size_t)(jq0 + tj) * M_DIM + (size_t)(iq0 + g);
        xl[k] = *reinterpret_cast<const float4*>(x + q[k]);
    }

    // ---- build cubic coeff table: 448 float4s from global cp (L2-hot) ----
    // out = c3*Pm1 + c2*P0 + c1*P1 + c0*P2 regrouped by powers of u:
    //   A = 0.5*Pm1 - 1.5*P0 + 1.5*P1 - 0.5*P2
    //   B = -0.5*Pm1 + 2*P0 - 2.5*P1 + P2
    //   C = 0.5*(P0 - P2)
    //   D = P1
    #pragma unroll
    for (int rep = 0; rep < 2; ++rep) {
        int i = t + rep * 256;
        if (i < TILE * NSEG) {
            int n = i / NSEG;                  // neuron-in-tile
            int s = i - n * NSEG;              // segment
            const float* p = cp + (size_t)(jq0 + n) * KPTS + s;
            float Pm1 = p[0], P0 = p[1], P1 = p[2], P2 = p[3];
            floatx4 cf;
            cf.x =  0.5f * Pm1 - 1.5f * P0 + 1.5f * P1 - 0.5f * P2;
            cf.y = -0.5f * Pm1 + 2.0f * P0 - 2.5f * P1 +        P2;
            cf.z =  0.5f * (P0 - P2);
            cf.w =  P1;
            coefs[i] = cf;
        }
    }

    // ---- seg-pack staging: 4 x ds_write_b32 per thread ----
    #pragma unroll
    for (int k = 0; k < 4; ++k) {
        int f = t + k * 256;
        int r = f >> 4, c4w = (f & 15);
        unsigned int w = (unsigned)seg_of(tv[k].x)
                       | ((unsigned)seg_of(tv[k].y) << 8)
                       | ((unsigned)seg_of(tv[k].z) << 16)
                       | ((unsigned)seg_of(tv[k].w) << 24);
        segp[r * PITCHW + c4w] = w;
    }
    __syncthreads();

    // ---- 4 packed seg words serve all 16 outputs ----
    unsigned int sw[4];
    #pragma unroll
    for (int e = 0; e < 4; ++e)
        sw[e] = segp[(g + e) * PITCHW + a];

    // ---- compute + store ----
    #pragma unroll
    for (int k = 0; k < 4; ++k) {
        int tj = 4 * a + k;
        float xle[4] = {xl[k].x, xl[k].y, xl[k].z, xl[k].w};
        float res[4];
        #pragma unroll
        for (int e = 0; e < 4; ++e) {
            int seg = (sw[e] >> (8 * k)) & 0xff;
            floatx4 cf = coefs[tj * NSEG + seg];   // one ds_read_b128
            float xv = xle[e];
            float tt = 2.0f * xv;                  // x / 0.5
            float u  = tt - floorf(tt);
            res[e] = ((cf.x * u + cf.y) * u + cf.z) * u + cf.w;
        }
        floatx4 ov = {res[0], res[1], res[2], res[3]};
        __builtin_nontemporal_store(ov, reinterpret_cast<floatx4*>(out + q[k]));
    }
}

extern "C" void kernel_launch(void* const* d_in, const int* in_sizes, int n_in,
                              void* d_out, int out_size, void* d_ws, size_t ws_size,
                              hipStream_t stream) {
    const float* x  = (const float*)d_in[0];   // (M, N) f32
    const float* cp = (const float*)d_in[1];   // (N, K) f32
    float* out = (float*)d_out;                // (M, N) f32

    dim3 grid(M_DIM / TILE, N_DIM / TILE);     // (128, 32)
    dim3 block(256);
    catmull_rom_kernel<<<grid, block, 0, stream>>>(x, cp, out);
}